// Round 7
// baseline (335.482 us; speedup 1.0000x reference)
//
#include <hip/hip_runtime.h>
#include <hip/hip_bf16.h>
#include <cstdint>
#include <cstddef>

#define KDIM 4096   // out features
#define NDIM 4096   // in features (contraction dim)
#define NGRP 32
#define GSZ  128
#define MDIM 8192   // 4 * 2048 rows of x
#define NT   (NDIM / 64)   // 64 K-tiles of BK=64

typedef unsigned short ushort_t;
typedef float f32x4 __attribute__((ext_vector_type(4)));
typedef float f32x16 __attribute__((ext_vector_type(16)));
typedef __bf16 bf16x8 __attribute__((ext_vector_type(8)));
typedef unsigned short u16x8 __attribute__((ext_vector_type(8)));
typedef int i32x4 __attribute__((ext_vector_type(4)));

// RTNE float -> bf16
__device__ __forceinline__ ushort_t f2bf(float f) {
    union { float f; unsigned u; } v; v.f = f;
    unsigned r = v.u + 0x7FFFu + ((v.u >> 16) & 1u);
    return (ushort_t)(r >> 16);
}

__device__ __forceinline__ void gload_lds16(const void* g, void* l) {
    __builtin_amdgcn_global_load_lds(
        (const __attribute__((address_space(1))) unsigned int*)g,
        (__attribute__((address_space(3))) unsigned int*)l,
        16, 0, 0);
}

// ---------------- Pass 1a: dequantize W -> bf16 [K, N] ----------------
__global__ __launch_bounds__(256) void dq_w_kernel(
    const int* __restrict__ Wq, const float* __restrict__ scales,
    const float* __restrict__ zeros, const int* __restrict__ mask,
    const float* __restrict__ scale2, ushort_t* __restrict__ Wb) {
    int gid = blockIdx.x * 256 + threadIdx.x;
    int e0 = gid * 8;
    int k = e0 >> 12;
    int n = e0 & (NDIM - 1);
    int g = n >> 7;
    float ss = scales[k * NGRP + g] * scale2[k];
    float z  = zeros[k * NGRP + g];
    i32x4 q0 = *(const i32x4*)(Wq + e0);
    i32x4 q1 = *(const i32x4*)(Wq + e0 + 4);
    i32x4 m0 = *(const i32x4*)(mask + e0);
    i32x4 m1 = *(const i32x4*)(mask + e0 + 4);
    u16x8 r;
#pragma unroll
    for (int i = 0; i < 4; ++i) r[i]     = f2bf(((float)q0[i] - z) * ss * (float)m0[i]);
#pragma unroll
    for (int i = 0; i < 4; ++i) r[4 + i] = f2bf(((float)q1[i] - z) * ss * (float)m1[i]);
    *(u16x8*)(Wb + e0) = r;
}

// ---------------- Pass 1b: convert x fp32 -> bf16 [M, N] ----------------
__global__ __launch_bounds__(256) void cvt_x_kernel(
    const float* __restrict__ x, ushort_t* __restrict__ Xb) {
    int gid = blockIdx.x * 256 + threadIdx.x;
    size_t e0 = (size_t)gid * 8;
    f32x4 a = *(const f32x4*)(x + e0);
    f32x4 b = *(const f32x4*)(x + e0 + 4);
    u16x8 r;
#pragma unroll
    for (int i = 0; i < 4; ++i) r[i] = f2bf(a[i]);
#pragma unroll
    for (int i = 0; i < 4; ++i) r[4 + i] = f2bf(b[i]);
    *(u16x8*)(Xb + e0) = r;
}

// ---------------- Pass 2: 256x256-tile bf16 GEMM, 32x32x16 MFMA ----------
// out[m][k] = sum_n Xb[m][n] * Wb[k][n] + bias[k]
// Identical schedule to the round-6-proven kernel (4-window TILE2, read
// pipelining, vmcnt(6) ledger, stages, barriers, swizzle). Only the MFMA
// shape changed 16x16x32 -> 32x32x16: the 16x16 instruction caps at 87% of
// the 32x32 rate (m119: 2176 vs 2495 TF); measured busy-rate was exactly
// 86.6% -> shape switch raises the per-busy-cycle ceiling ~15%.
// Fragments (32x32x16): A: lane reads row (lane&31), 8 contiguous k at
// k = ks*16 + (lane>>5)*8 -> 16B chunk = ks*2 + (lane>>5), XOR (row&7)
// swizzle unchanged (lanes distribute uniform-8 per chunk-column = the
// same conflict-free phasing the 16x16 reads measured 0 on).
// C/D (m74/m101, HW-verified): col = lane&31,
// row = (reg&3) + 8*(reg>>2) + 4*(lane>>5), reg 0..15.
// Per cluster: 8 MFMAs (2 m32-subtiles x 4 ks, interleaved acc chains).

#define LDS_SLOT 65536
#define LDS_A0   0
#define LDS_A1   16384
#define LDS_B0   32768
#define LDS_B1   49152

#define STAGE(ldsHalf, gbase) do { \
    gload_lds16((gbase) + goff0, (ldsHalf) + ldsoff0); \
    gload_lds16((gbase) + goff1, (ldsHalf) + ldsoff1); } while (0)

// A-fragment set: 2 m32-subtiles x 4 k-steps (8 x b128)
#define READ_A(S, H) do { \
    const char* Ab_ = lds + (S)*LDS_SLOT + (H)*16384 + rowA; \
    a00 = *(const bf16x8*)(Ab_ + cbk0); \
    a01 = *(const bf16x8*)(Ab_ + cbk1); \
    a02 = *(const bf16x8*)(Ab_ + cbk2); \
    a03 = *(const bf16x8*)(Ab_ + cbk3); \
    a10 = *(const bf16x8*)(Ab_ + 4096 + cbk0); \
    a11 = *(const bf16x8*)(Ab_ + 4096 + cbk1); \
    a12 = *(const bf16x8*)(Ab_ + 4096 + cbk2); \
    a13 = *(const bf16x8*)(Ab_ + 4096 + cbk3); \
} while (0)

// B-fragment set: 1 n32-subtile x 4 k-steps (4 x b128)
#define READ_B(S, NH, B0, B1, B2, B3) do { \
    const char* Bb_ = lds + (S)*LDS_SLOT + 32768 + (NH)*16384 + rowB; \
    B0 = *(const bf16x8*)(Bb_ + cbk0); \
    B1 = *(const bf16x8*)(Bb_ + cbk1); \
    B2 = *(const bf16x8*)(Bb_ + cbk2); \
    B3 = *(const bf16x8*)(Bb_ + cbk3); \
} while (0)

#define BAR    asm volatile("s_barrier" ::: "memory")
#define VMCNT6 asm volatile("s_waitcnt vmcnt(6)" ::: "memory")
#define VMCNT0 asm volatile("s_waitcnt vmcnt(0)" ::: "memory")
#define SB     __builtin_amdgcn_sched_barrier(0)

// 8 MFMAs: acc index = H*4 + m32*2 + NH; two interleaved dep-chains (m32)
#define CLUSTER8(H, NH, B0, B1, B2, B3) do { \
    SB; __builtin_amdgcn_s_setprio(1); \
    acc[(H)*4+0+(NH)] = __builtin_amdgcn_mfma_f32_32x32x16_bf16(a00, B0, acc[(H)*4+0+(NH)], 0,0,0); \
    acc[(H)*4+2+(NH)] = __builtin_amdgcn_mfma_f32_32x32x16_bf16(a10, B0, acc[(H)*4+2+(NH)], 0,0,0); \
    acc[(H)*4+0+(NH)] = __builtin_amdgcn_mfma_f32_32x32x16_bf16(a01, B1, acc[(H)*4+0+(NH)], 0,0,0); \
    acc[(H)*4+2+(NH)] = __builtin_amdgcn_mfma_f32_32x32x16_bf16(a11, B1, acc[(H)*4+2+(NH)], 0,0,0); \
    acc[(H)*4+0+(NH)] = __builtin_amdgcn_mfma_f32_32x32x16_bf16(a02, B2, acc[(H)*4+0+(NH)], 0,0,0); \
    acc[(H)*4+2+(NH)] = __builtin_amdgcn_mfma_f32_32x32x16_bf16(a12, B2, acc[(H)*4+2+(NH)], 0,0,0); \
    acc[(H)*4+0+(NH)] = __builtin_amdgcn_mfma_f32_32x32x16_bf16(a03, B3, acc[(H)*4+0+(NH)], 0,0,0); \
    acc[(H)*4+2+(NH)] = __builtin_amdgcn_mfma_f32_32x32x16_bf16(a13, B3, acc[(H)*4+2+(NH)], 0,0,0); \
    __builtin_amdgcn_s_setprio(0); SB; \
} while (0)

// One K-tile: same 4-window skeleton as round 6 (proven invariants).
#define TILE2(S, P0,P1,P2,P3, Q0,Q1,Q2,Q3, ST0, ST1, ST2, ST3, BND) do { \
    ST0; \
    CLUSTER8(0, 0, P0,P1,P2,P3); \
    READ_B(S, 1, Q0,Q1,Q2,Q3); \
    BAR; \
    ST1; \
    CLUSTER8(0, 1, Q0,Q1,Q2,Q3); \
    READ_A(S, 1); \
    BAR; \
    ST2; \
    CLUSTER8(1, 1, Q0,Q1,Q2,Q3); \
    BAR; \
    ST3; \
    BND; \
    BAR; \
    READ_B((S)^1, 0, Q0,Q1,Q2,Q3); \
    CLUSTER8(1, 0, P0,P1,P2,P3); \
    READ_A((S)^1, 0); \
} while (0)

__global__ __launch_bounds__(512, 2) void gemm8p_kernel(
    const ushort_t* __restrict__ Xb, const ushort_t* __restrict__ Wb,
    const float* __restrict__ bias, float* __restrict__ out) {
    extern __shared__ char lds[];

    const int tid   = threadIdx.x;
    const int lane  = tid & 63;
    const int wid   = tid >> 6;      // 0..7
    const int wm    = wid >> 2;      // 0..1  (M sub-block within each half)
    const int wn    = wid & 3;       // 0..3  (N sub-block within each half)
    const int rl    = lane & 31;     // row/col within 32-tile
    const int kg    = lane >> 5;     // k-group (0/1)

    // T1: bijective XCD swizzle (512 % 8 == 0)
    const int orig  = blockIdx.x;
    const int wgid  = ((orig & 7) << 6) | (orig >> 3);
    const int ntile = wgid & 15;     // 16 N-tiles
    const int mtile = wgid >> 4;     // 32 M-tiles
    const int m0 = mtile << 8;
    const int n0 = ntile << 8;

    // stage addressing: granule g = l*512 + tid; LDS linear; global pre-swizzled
    const int g0 = tid, g1 = 512 + tid;
    const size_t goff0 = (size_t)(g0 >> 3) * NDIM + (size_t)((((g0 & 7) ^ ((g0 >> 3) & 7))) << 3);
    const size_t goff1 = (size_t)(g1 >> 3) * NDIM + (size_t)((((g1 & 7) ^ ((g1 >> 3) & 7))) << 3);
    const int ldsoff0 = (wid << 10);          // wave-uniform base, load 0
    const int ldsoff1 = 8192 + (wid << 10);   // load 1

    // fragment read offsets (bytes within a [128][64] bf16 half-buffer)
    const int rowA = ((wm << 6) + rl) << 7;          // (wm*64 + rl)*128
    const int rowB = ((wn << 5) + rl) << 7;          // (wn*32 + rl)*128
    const int cbk0 = ((0 + kg) ^ (rl & 7)) << 4;     // ks=0 chunk (swizzled)
    const int cbk1 = ((2 + kg) ^ (rl & 7)) << 4;     // ks=1
    const int cbk2 = ((4 + kg) ^ (rl & 7)) << 4;     // ks=2
    const int cbk3 = ((6 + kg) ^ (rl & 7)) << 4;     // ks=3

    f32x16 acc[8];
#pragma unroll
    for (int i = 0; i < 8; ++i)
#pragma unroll
        for (int j = 0; j < 16; ++j) acc[i][j] = 0.f;

    const ushort_t* Xrow0 = Xb + (size_t)m0 * NDIM;
    const ushort_t* Xrow1 = Xb + (size_t)(m0 + 128) * NDIM;
    const ushort_t* Wrow0 = Wb + (size_t)n0 * NDIM;
    const ushort_t* Wrow1 = Wb + (size_t)(n0 + 128) * NDIM;

    // fragment registers: a = current A-half (2 m32 x 4 ks); p/q = B0/B1 sets
    bf16x8 a00, a01, a02, a03, a10, a11, a12, a13;
    bf16x8 p0, p1, p2, p3, q0, q1, q2, q3;

    // Prologue: tile 0 complete into slot 0 (8 loads), then B0[1],B1[1],A1[1]
    // into slot 1 (6 loads). vmcnt(6) forces tile 0 landed. Then read tile 0's
    // (0,0)-operands (one-time startup drain).
    STAGE(lds + 0*LDS_SLOT + LDS_A0, Xrow0 + 0);
    STAGE(lds + 0*LDS_SLOT + LDS_B0, Wrow0 + 0);
    STAGE(lds + 0*LDS_SLOT + LDS_B1, Wrow1 + 0);
    STAGE(lds + 0*LDS_SLOT + LDS_A1, Xrow1 + 0);
    STAGE(lds + 1*LDS_SLOT + LDS_B0, Wrow0 + 64);
    STAGE(lds + 1*LDS_SLOT + LDS_B1, Wrow1 + 64);
    STAGE(lds + 1*LDS_SLOT + LDS_A1, Xrow1 + 64);
    VMCNT6;
    BAR;
    READ_A(0, 0);
    READ_B(0, 0, p0, p1, p2, p3);

    // Hot loop: tiles 0..61 (all stage indices statically valid).
#pragma unroll 1
    for (int kt2 = 0; kt2 < NT / 2 - 1; ++kt2) {
        const int te = 2 * kt2, to = te + 1;
        TILE2(0, p0,p1,p2,p3, q0,q1,q2,q3,
              STAGE(lds + 1*LDS_SLOT + LDS_A0, Xrow0 + (te + 1) * 64),
              STAGE(lds + 0*LDS_SLOT + LDS_B0, Wrow0 + (te + 2) * 64),
              STAGE(lds + 0*LDS_SLOT + LDS_B1, Wrow1 + (te + 2) * 64),
              STAGE(lds + 0*LDS_SLOT + LDS_A1, Xrow1 + (te + 2) * 64),
              VMCNT6);
        TILE2(1, q0,q1,q2,q3, p0,p1,p2,p3,
              STAGE(lds + 0*LDS_SLOT + LDS_A0, Xrow0 + (to + 1) * 64),
              STAGE(lds + 1*LDS_SLOT + LDS_B0, Wrow0 + (to + 2) * 64),
              STAGE(lds + 1*LDS_SLOT + LDS_B1, Wrow1 + (to + 2) * 64),
              STAGE(lds + 1*LDS_SLOT + LDS_A1, Xrow1 + (to + 2) * 64),
              VMCNT6);
    }
    // Peeled tile 62 (slot 0): only A0[63] stage; vmcnt(0) at its boundary
    // (tail: steady forcing breaks). Its pre-reads fetch tile 63's operands.
    TILE2(0, p0,p1,p2,p3, q0,q1,q2,q3,
          STAGE(lds + 1*LDS_SLOT + LDS_A0, Xrow0 + 63 * 64),
          (void)0, (void)0, (void)0,
          VMCNT0);
    // Peeled tile 63 (slot 1): no stages; trailing pre-reads are dead (DCE).
    TILE2(1, q0,q1,q2,q3, p0,p1,p2,p3,
          (void)0, (void)0, (void)0, (void)0, (void)0);

    // Epilogue: 32x32 C/D layout: col = lane&31,
    // row = (reg&3) + 8*(reg>>2) + 4*kg  (m74/m101 verified).
    const float bv0 = bias[n0 +       (wn << 5) + rl];
    const float bv1 = bias[n0 + 128 + (wn << 5) + rl];
#pragma unroll
    for (int h = 0; h < 2; ++h)
#pragma unroll
        for (int m32 = 0; m32 < 2; ++m32)
#pragma unroll
            for (int nh = 0; nh < 2; ++nh) {
                const int rbase = m0 + (h << 7) + (wm << 6) + (m32 << 5) + (kg << 2);
                const int col   = n0 + (nh << 7) + (wn << 5) + rl;
                const float bv  = nh ? bv1 : bv0;
#pragma unroll
                for (int reg = 0; reg < 16; ++reg) {
                    const int row = rbase + (reg & 3) + ((reg >> 2) << 3);
                    out[(size_t)row * KDIM + col] = acc[h*4 + m32*2 + nh][reg] + bv;
                }
            }
}

// ---------------- Fallback (only if ws too small): naive fused ----------------
__global__ __launch_bounds__(256) void naive_kernel(
    const float* __restrict__ x, const int* __restrict__ Wq,
    const float* __restrict__ scales, const float* __restrict__ zeros,
    const int* __restrict__ mask, const float* __restrict__ scale2,
    const float* __restrict__ bias, float* __restrict__ out) {
    size_t o = (size_t)blockIdx.x * 256 + threadIdx.x;
    int m = (int)(o >> 12);
    int k = (int)(o & (KDIM - 1));
    const float* xr = x + (size_t)m * NDIM;
    const int* wr = Wq + (size_t)k * NDIM;
    const int* mr = mask + (size_t)k * NDIM;
    float s2 = scale2[k];
    float acc = 0.f;
    for (int g = 0; g < NGRP; ++g) {
        float ss = scales[k * NGRP + g] * s2;
        float z = zeros[k * NGRP + g];
        for (int n = g * GSZ; n < (g + 1) * GSZ; ++n)
            acc += xr[n] * (((float)wr[n] - z) * ss * (float)mr[n]);
    }
    out[o] = acc + bias[k];
}

extern "C" void kernel_launch(void* const* d_in, const int* in_sizes, int n_in,
                              void* d_out, int out_size, void* d_ws, size_t ws_size,
                              hipStream_t stream) {
    const float* x      = (const float*)d_in[0];
    const int*   Wq     = (const int*)d_in[1];
    const float* scales = (const float*)d_in[2];
    const float* zeros  = (const float*)d_in[3];
    const int*   mask   = (const int*)d_in[4];
    const float* scale2 = (const float*)d_in[5];
    const float* bias   = (const float*)d_in[6];
    float* out = (float*)d_out;

    const size_t needW = (size_t)KDIM * NDIM * sizeof(ushort_t);  // 32 MiB
    const size_t needX = (size_t)MDIM * NDIM * sizeof(ushort_t);  // 64 MiB

    if (ws_size >= needW + needX) {
        ushort_t* Wb = (ushort_t*)d_ws;
        ushort_t* Xb = (ushort_t*)((char*)d_ws + needW);
        hipLaunchKernelGGL(dq_w_kernel, dim3((KDIM * NDIM / 8) / 256), dim3(256),
                           0, stream, Wq, scales, zeros, mask, scale2, Wb);
        hipLaunchKernelGGL(cvt_x_kernel, dim3((MDIM * NDIM / 8) / 256), dim3(256),
                           0, stream, x, Xb);
        hipFuncSetAttribute((const void*)gemm8p_kernel,
                            hipFuncAttributeMaxDynamicSharedMemorySize, 131072);
        hipLaunchKernelGGL(gemm8p_kernel, dim3((MDIM / 256) * (KDIM / 256)), dim3(512),
                           131072, stream, Xb, Wb, bias, out);
    } else {
        hipLaunchKernelGGL(naive_kernel, dim3((MDIM * KDIM) / 256), dim3(256),
                           0, stream, x, Wq, scales, zeros, mask, scale2, bias, out);
    }
}

// Round 9
// 274.883 us; speedup vs baseline: 1.2205x; 1.2205x over previous
//
#include <hip/hip_runtime.h>
#include <hip/hip_bf16.h>
#include <cstdint>
#include <cstddef>

#define KDIM 4096   // out features
#define NDIM 4096   // in features (contraction dim)
#define NGRP 32
#define GSZ  128
#define MDIM 8192   // 4 * 2048 rows of x
#define NT   (NDIM / 64)   // 64 K-tiles of BK=64

typedef unsigned short ushort_t;
typedef float f32x4 __attribute__((ext_vector_type(4)));
typedef __bf16 bf16x8 __attribute__((ext_vector_type(8)));
typedef unsigned short u16x8 __attribute__((ext_vector_type(8)));
typedef int i32x4 __attribute__((ext_vector_type(4)));

// RTNE float -> bf16
__device__ __forceinline__ ushort_t f2bf(float f) {
    union { float f; unsigned u; } v; v.f = f;
    unsigned r = v.u + 0x7FFFu + ((v.u >> 16) & 1u);
    return (ushort_t)(r >> 16);
}

__device__ __forceinline__ void gload_lds16(const void* g, void* l) {
    __builtin_amdgcn_global_load_lds(
        (const __attribute__((address_space(1))) unsigned int*)g,
        (__attribute__((address_space(3))) unsigned int*)l,
        16, 0, 0);
}

// ---------------- Pass 1a: dequantize W -> bf16 [K, N] ----------------
__global__ __launch_bounds__(256) void dq_w_kernel(
    const int* __restrict__ Wq, const float* __restrict__ scales,
    const float* __restrict__ zeros, const int* __restrict__ mask,
    const float* __restrict__ scale2, ushort_t* __restrict__ Wb) {
    int gid = blockIdx.x * 256 + threadIdx.x;
    int e0 = gid * 8;
    int k = e0 >> 12;
    int n = e0 & (NDIM - 1);
    int g = n >> 7;
    float ss = scales[k * NGRP + g] * scale2[k];
    float z  = zeros[k * NGRP + g];
    i32x4 q0 = *(const i32x4*)(Wq + e0);
    i32x4 q1 = *(const i32x4*)(Wq + e0 + 4);
    i32x4 m0 = *(const i32x4*)(mask + e0);
    i32x4 m1 = *(const i32x4*)(mask + e0 + 4);
    u16x8 r;
#pragma unroll
    for (int i = 0; i < 4; ++i) r[i]     = f2bf(((float)q0[i] - z) * ss * (float)m0[i]);
#pragma unroll
    for (int i = 0; i < 4; ++i) r[4 + i] = f2bf(((float)q1[i] - z) * ss * (float)m1[i]);
    *(u16x8*)(Wb + e0) = r;
}

// ---------------- Pass 1b: convert x fp32 -> bf16 [M, N] ----------------
__global__ __launch_bounds__(256) void cvt_x_kernel(
    const float* __restrict__ x, ushort_t* __restrict__ Xb) {
    int gid = blockIdx.x * 256 + threadIdx.x;
    size_t e0 = (size_t)gid * 8;
    f32x4 a = *(const f32x4*)(x + e0);
    f32x4 b = *(const f32x4*)(x + e0 + 4);
    u16x8 r;
#pragma unroll
    for (int i = 0; i < 4; ++i) r[i] = f2bf(a[i]);
#pragma unroll
    for (int i = 0; i < 4; ++i) r[4 + i] = f2bf(b[i]);
    *(u16x8*)(Xb + e0) = r;
}

// ---------------- Pass 2: 256x256-tile bf16 GEMM, 2-barrier tiles --------
// out[m][k] = sum_n Xb[m][n] * Wb[k][n] + bias[k]
// Round-8 postmortem: a staged region is readable only if EVERY wave's
// forcing vmcnt precedes a BARRIER that precedes the read (vmcnt is
// per-wave; the DMA landing of another wave's load is otherwise unordered).
// Fixed stage schedule (A1/B1 staged 1 tile ahead at tile START; A0/B0
// staged 2 tiles ahead at tile MID):
//   tile t (slot S=t&1), steady outstanding at entry: {B0[t+1],A0[t+1]}=4.
//   start: stage A1[t+1]->S^1, B1[t+1]->S^1            (outstanding 8)
//   win1:  readB1[t] ; (0,0)P ; (0,1)Q ; readA1[t]
//   WMID = vmcnt(4)  -> forces B0[t+1],A0[t+1]         (leaves 4)
//   mid-BAR                                            <- their reads follow
//   mid:   stage B0[t+2]->S, A0[t+2]->S                (outstanding 8)
//   win2:  (1,1)Q ; pre-read B0[t+1] ; (1,0)P ; pre-read A0[t+1]
//   WEND = vmcnt(4)  -> forces A1[t+1],B1[t+1]         (leaves 4)
//   end-BAR                                            <- t+1 win1 reads them
// Landing: every read's region forced by all waves one barrier earlier ✓.
// Stage->force gap ~1 tile (~1300cyc > 900 HBM) -> waits free.
// Overwrite safety (stage >= 1 barrier after region's last read retired;
// reads retire via data-dep before their consumer cluster):
//   A1[t+1]->S^1 @start: A1[t-1] last read t-1 win1, retired < t-1 (1,1)
//     < t-1 end-BAR < this stage.
//   B1[t+1]->S^1 @start: B1[t-1] last read t-1 win1, retired < t-1 (0,1)
//     < t-1 mid-BAR < t-1 end-BAR < this stage.
//   B0[t+2]->S @mid: B0[t] last read = t-1 win2 pre-read, retired < t (0,0)
//     < t mid-BAR < this stage.
//   A0[t+2]->S @mid: A0[t] last read = t-1 win2 pre-read, retired < t (0,0)
//     < t mid-BAR < this stage.
// Prologue: 12 loads, vmcnt(4) forces tile-0's 4 halves, leaves
// {B0[1],A0[1]} = exact steady entry. Tail: tile 62 WEND vmcnt(0); 63 bare.
// 16x16x32 MFMA, round-6-proven fragments/swizzle/reads (24 b128/tile/wave).

#define LDS_SLOT 65536
#define LDS_A0   0
#define LDS_A1   16384
#define LDS_B0   32768
#define LDS_B1   49152

#define STAGE(ldsHalf, gbase) do { \
    gload_lds16((gbase) + goff0, (ldsHalf) + ldsoff0); \
    gload_lds16((gbase) + goff1, (ldsHalf) + ldsoff1); } while (0)

#define READ_A(S, QM) do { \
    const char* Ab_ = lds + (S)*LDS_SLOT + (QM)*16384 + rowA; \
    a00 = *(const bf16x8*)(Ab_ + 0*2048 + cb0); \
    a10 = *(const bf16x8*)(Ab_ + 1*2048 + cb0); \
    a20 = *(const bf16x8*)(Ab_ + 2*2048 + cb0); \
    a30 = *(const bf16x8*)(Ab_ + 3*2048 + cb0); \
    a01 = *(const bf16x8*)(Ab_ + 0*2048 + cb1); \
    a11 = *(const bf16x8*)(Ab_ + 1*2048 + cb1); \
    a21 = *(const bf16x8*)(Ab_ + 2*2048 + cb1); \
    a31 = *(const bf16x8*)(Ab_ + 3*2048 + cb1); \
} while (0)

#define READ_B(S, QN, B00, B10, B01, B11) do { \
    const char* Bb_ = lds + (S)*LDS_SLOT + 32768 + (QN)*16384 + rowB; \
    B00 = *(const bf16x8*)(Bb_ + 0*2048 + cb0); \
    B10 = *(const bf16x8*)(Bb_ + 1*2048 + cb0); \
    B01 = *(const bf16x8*)(Bb_ + 0*2048 + cb1); \
    B11 = *(const bf16x8*)(Bb_ + 1*2048 + cb1); \
} while (0)

#define MFMA16(QM, QN, B00, B10, B01, B11) do { \
    acc[(QM)*4+0][(QN)*2+0] = __builtin_amdgcn_mfma_f32_16x16x32_bf16(a00, B00, acc[(QM)*4+0][(QN)*2+0], 0,0,0); \
    acc[(QM)*4+1][(QN)*2+0] = __builtin_amdgcn_mfma_f32_16x16x32_bf16(a10, B00, acc[(QM)*4+1][(QN)*2+0], 0,0,0); \
    acc[(QM)*4+2][(QN)*2+0] = __builtin_amdgcn_mfma_f32_16x16x32_bf16(a20, B00, acc[(QM)*4+2][(QN)*2+0], 0,0,0); \
    acc[(QM)*4+3][(QN)*2+0] = __builtin_amdgcn_mfma_f32_16x16x32_bf16(a30, B00, acc[(QM)*4+3][(QN)*2+0], 0,0,0); \
    acc[(QM)*4+0][(QN)*2+1] = __builtin_amdgcn_mfma_f32_16x16x32_bf16(a00, B10, acc[(QM)*4+0][(QN)*2+1], 0,0,0); \
    acc[(QM)*4+1][(QN)*2+1] = __builtin_amdgcn_mfma_f32_16x16x32_bf16(a10, B10, acc[(QM)*4+1][(QN)*2+1], 0,0,0); \
    acc[(QM)*4+2][(QN)*2+1] = __builtin_amdgcn_mfma_f32_16x16x32_bf16(a20, B10, acc[(QM)*4+2][(QN)*2+1], 0,0,0); \
    acc[(QM)*4+3][(QN)*2+1] = __builtin_amdgcn_mfma_f32_16x16x32_bf16(a30, B10, acc[(QM)*4+3][(QN)*2+1], 0,0,0); \
    acc[(QM)*4+0][(QN)*2+0] = __builtin_amdgcn_mfma_f32_16x16x32_bf16(a01, B01, acc[(QM)*4+0][(QN)*2+0], 0,0,0); \
    acc[(QM)*4+1][(QN)*2+0] = __builtin_amdgcn_mfma_f32_16x16x32_bf16(a11, B01, acc[(QM)*4+1][(QN)*2+0], 0,0,0); \
    acc[(QM)*4+2][(QN)*2+0] = __builtin_amdgcn_mfma_f32_16x16x32_bf16(a21, B01, acc[(QM)*4+2][(QN)*2+0], 0,0,0); \
    acc[(QM)*4+3][(QN)*2+0] = __builtin_amdgcn_mfma_f32_16x16x32_bf16(a31, B01, acc[(QM)*4+3][(QN)*2+0], 0,0,0); \
    acc[(QM)*4+0][(QN)*2+1] = __builtin_amdgcn_mfma_f32_16x16x32_bf16(a01, B11, acc[(QM)*4+0][(QN)*2+1], 0,0,0); \
    acc[(QM)*4+1][(QN)*2+1] = __builtin_amdgcn_mfma_f32_16x16x32_bf16(a11, B11, acc[(QM)*4+1][(QN)*2+1], 0,0,0); \
    acc[(QM)*4+2][(QN)*2+1] = __builtin_amdgcn_mfma_f32_16x16x32_bf16(a21, B11, acc[(QM)*4+2][(QN)*2+1], 0,0,0); \
    acc[(QM)*4+3][(QN)*2+1] = __builtin_amdgcn_mfma_f32_16x16x32_bf16(a31, B11, acc[(QM)*4+3][(QN)*2+1], 0,0,0); \
} while (0)

#define BAR    asm volatile("s_barrier" ::: "memory")
#define VMCNT4 asm volatile("s_waitcnt vmcnt(4)" ::: "memory")
#define VMCNT0 asm volatile("s_waitcnt vmcnt(0)" ::: "memory")
#define NOWAIT (void)0
#define SB     __builtin_amdgcn_sched_barrier(0)

#define CLUSTER(QM, QN, B00, B10, B01, B11) do { \
    SB; __builtin_amdgcn_s_setprio(1); \
    MFMA16(QM, QN, B00, B10, B01, B11); \
    __builtin_amdgcn_s_setprio(0); SB; \
} while (0)

// One K-tile, 2 barriers. Entry: a=A0[t], P=B0[t] (regs),
// outstanding={B0[t+1],A0[t+1]}. Exit: a=A0[t+1], Q=B0[t+1] (P/Q swap).
#define TILE2B(S, P00,P10,P01,P11, Q00,Q10,Q01,Q11, \
               STA1, STB1, STB0, STA0, WMID, WEND) do { \
    STA1; STB1; \
    READ_B(S, 1, Q00,Q10,Q01,Q11); \
    CLUSTER(0, 0, P00,P10,P01,P11); \
    CLUSTER(0, 1, Q00,Q10,Q01,Q11); \
    READ_A(S, 1); \
    WMID; \
    BAR; \
    STB0; STA0; \
    CLUSTER(1, 1, Q00,Q10,Q01,Q11); \
    READ_B((S)^1, 0, Q00,Q10,Q01,Q11); \
    CLUSTER(1, 0, P00,P10,P01,P11); \
    READ_A((S)^1, 0); \
    WEND; \
    BAR; \
} while (0)

__global__ __launch_bounds__(512, 2) void gemm8p_kernel(
    const ushort_t* __restrict__ Xb, const ushort_t* __restrict__ Wb,
    const float* __restrict__ bias, float* __restrict__ out) {
    extern __shared__ char lds[];

    const int tid   = threadIdx.x;
    const int lane  = tid & 63;
    const int wid   = tid >> 6;      // 0..7
    const int wm    = wid >> 2;      // 0..1  (M sub-block within each half)
    const int wn    = wid & 3;       // 0..3  (N sub-block within each half)
    const int fr    = lane & 15;
    const int khalf = lane >> 4;     // 0..3

    // T1: bijective XCD swizzle (512 % 8 == 0)
    const int orig  = blockIdx.x;
    const int wgid  = ((orig & 7) << 6) | (orig >> 3);
    const int ntile = wgid & 15;     // 16 N-tiles
    const int mtile = wgid >> 4;     // 32 M-tiles
    const int m0 = mtile << 8;
    const int n0 = ntile << 8;

    // stage addressing: granule g = l*512 + tid; LDS linear; global pre-swizzled
    const int g0 = tid, g1 = 512 + tid;
    const size_t goff0 = (size_t)(g0 >> 3) * NDIM + (size_t)((((g0 & 7) ^ ((g0 >> 3) & 7))) << 3);
    const size_t goff1 = (size_t)(g1 >> 3) * NDIM + (size_t)((((g1 & 7) ^ ((g1 >> 3) & 7))) << 3);
    const int ldsoff0 = (wid << 10);          // wave-uniform base, load 0
    const int ldsoff1 = 8192 + (wid << 10);   // load 1

    // fragment read offsets (bytes within a [128][64] bf16 half-buffer)
    const int rowA = ((wm << 6) + fr) << 7;               // (wm*64+fr)*128
    const int rowB = ((wn << 5) + fr) << 7;               // (wn*32+fr)*128
    const int cb0  = ((khalf)     ^ (fr & 7)) << 4;       // kk=0 chunk (swizzled)
    const int cb1  = ((4 + khalf) ^ (fr & 7)) << 4;       // kk=1 chunk

    f32x4 acc[8][4];
#pragma unroll
    for (int i = 0; i < 8; ++i)
#pragma unroll
        for (int j = 0; j < 4; ++j) { f32x4 z = {0.f,0.f,0.f,0.f}; acc[i][j] = z; }

    const ushort_t* Xrow0 = Xb + (size_t)m0 * NDIM;
    const ushort_t* Xrow1 = Xb + (size_t)(m0 + 128) * NDIM;
    const ushort_t* Wrow0 = Wb + (size_t)n0 * NDIM;
    const ushort_t* Wrow1 = Wb + (size_t)(n0 + 128) * NDIM;

    // fragment registers: a = current A-half; p/q = B0/B1 (roles alternate)
    bf16x8 a00, a10, a20, a30, a01, a11, a21, a31;
    bf16x8 p00, p10, p01, p11, q00, q10, q01, q11;

    // Prologue: 12 loads in order {A0[0],B0[0],A1[0],B1[0], B0[1],A0[1]};
    // vmcnt(4) forces tile 0's four halves, leaves {B0[1],A0[1]} flying =
    // exact steady-state entry. BAR (cross-wave), then one-time startup
    // reads of tile-0's (0,0) operands.
    STAGE(lds + 0*LDS_SLOT + LDS_A0, Xrow0 + 0);
    STAGE(lds + 0*LDS_SLOT + LDS_B0, Wrow0 + 0);
    STAGE(lds + 0*LDS_SLOT + LDS_A1, Xrow1 + 0);
    STAGE(lds + 0*LDS_SLOT + LDS_B1, Wrow1 + 0);
    STAGE(lds + 1*LDS_SLOT + LDS_B0, Wrow0 + 64);
    STAGE(lds + 1*LDS_SLOT + LDS_A0, Xrow0 + 64);
    VMCNT4;
    BAR;
    READ_A(0, 0);
    READ_B(0, 0, p00, p10, p01, p11);

    // Hot loop: tiles 0..61.
#pragma unroll 1
    for (int kt2 = 0; kt2 < NT / 2 - 1; ++kt2) {
        const int te = 2 * kt2, to = te + 1;
        TILE2B(0, p00,p10,p01,p11, q00,q10,q01,q11,
               STAGE(lds + 1*LDS_SLOT + LDS_A1, Xrow1 + (te + 1) * 64),
               STAGE(lds + 1*LDS_SLOT + LDS_B1, Wrow1 + (te + 1) * 64),
               STAGE(lds + 0*LDS_SLOT + LDS_B0, Wrow0 + (te + 2) * 64),
               STAGE(lds + 0*LDS_SLOT + LDS_A0, Xrow0 + (te + 2) * 64),
               VMCNT4, VMCNT4);
        TILE2B(1, q00,q10,q01,q11, p00,p10,p01,p11,
               STAGE(lds + 0*LDS_SLOT + LDS_A1, Xrow1 + (to + 1) * 64),
               STAGE(lds + 0*LDS_SLOT + LDS_B1, Wrow1 + (to + 1) * 64),
               STAGE(lds + 1*LDS_SLOT + LDS_B0, Wrow0 + (to + 2) * 64),
               STAGE(lds + 1*LDS_SLOT + LDS_A0, Xrow0 + (to + 2) * 64),
               VMCNT4, VMCNT4);
    }
    // Peeled tile 62 (S=0): start stages A1[63],B1[63]; no mid stages.
    // WMID vmcnt(4) forces B0[63],A0[63] (outstanding 8, same as steady);
    // WEND vmcnt(0) forces A1[63],B1[63] (last 4).
    TILE2B(0, p00,p10,p01,p11, q00,q10,q01,q11,
           STAGE(lds + 1*LDS_SLOT + LDS_A1, Xrow1 + 63 * 64),
           STAGE(lds + 1*LDS_SLOT + LDS_B1, Wrow1 + 63 * 64),
           NOWAIT, NOWAIT,
           VMCNT4, VMCNT0);
    // Peeled tile 63 (S=1): no stages, no waits; win2 pre-reads are dead.
    TILE2B(1, q00,q10,q01,q11, p00,p10,p01,p11,
           NOWAIT, NOWAIT, NOWAIT, NOWAIT, NOWAIT, NOWAIT);

    // Epilogue: C/D layout col=lane&15, row=(lane>>4)*4+reg.
    // row(i) = m0 + (i>>2)*128 + wm*64 + (i&3)*16 + khalf*4 + q
    // col(j) = n0 + (j>>1)*128 + wn*32 + (j&1)*16 + fr
    float bv[4];
#pragma unroll
    for (int j = 0; j < 4; ++j)
        bv[j] = bias[n0 + ((j >> 1) << 7) + (wn << 5) + ((j & 1) << 4) + fr];
#pragma unroll
    for (int i = 0; i < 8; ++i) {
        const int row = m0 + ((i >> 2) << 7) + (wm << 6) + ((i & 3) << 4) + (khalf << 2);
#pragma unroll
        for (int j = 0; j < 4; ++j) {
            const int col = n0 + ((j >> 1) << 7) + (wn << 5) + ((j & 1) << 4) + fr;
#pragma unroll
            for (int q = 0; q < 4; ++q)
                out[(size_t)(row + q) * KDIM + col] = acc[i][j][q] + bv[j];
        }
    }
}

// ---------------- Fallback (only if ws too small): naive fused ----------------
__global__ __launch_bounds__(256) void naive_kernel(
    const float* __restrict__ x, const int* __restrict__ Wq,
    const float* __restrict__ scales, const float* __restrict__ zeros,
    const int* __restrict__ mask, const float* __restrict__ scale2,
    const float* __restrict__ bias, float* __restrict__ out) {
    size_t o = (size_t)blockIdx.x * 256 + threadIdx.x;
    int m = (int)(o >> 12);
    int k = (int)(o & (KDIM - 1));
    const float* xr = x + (size_t)m * NDIM;
    const int* wr = Wq + (size_t)k * NDIM;
    const int* mr = mask + (size_t)k * NDIM;
    float s2 = scale2[k];
    float acc = 0.f;
    for (int g = 0; g < NGRP; ++g) {
        float ss = scales[k * NGRP + g] * s2;
        float z = zeros[k * NGRP + g];
        for (int n = g * GSZ; n < (g + 1) * GSZ; ++n)
            acc += xr[n] * (((float)wr[n] - z) * ss * (float)mr[n]);
    }
    out[o] = acc + bias[k];
}

extern "C" void kernel_launch(void* const* d_in, const int* in_sizes, int n_in,
                              void* d_out, int out_size, void* d_ws, size_t ws_size,
                              hipStream_t stream) {
    const float* x      = (const float*)d_in[0];
    const int*   Wq     = (const int*)d_in[1];
    const float* scales = (const float*)d_in[2];
    const float* zeros  = (const float*)d_in[3];
    const int*   mask   = (const int*)d_in[4];
    const float* scale2 = (const float*)d_in[5];
    const float* bias   = (const float*)d_in[6];
    float* out = (float*)d_out;

    const size_t needW = (size_t)KDIM * NDIM * sizeof(ushort_t);  // 32 MiB
    const size_t needX = (size_t)MDIM * NDIM * sizeof(ushort_t);  // 64 MiB

    if (ws_size >= needW + needX) {
        ushort_t* Wb = (ushort_t*)d_ws;
        ushort_t* Xb = (ushort_t*)((char*)d_ws + needW);
        hipLaunchKernelGGL(dq_w_kernel, dim3((KDIM * NDIM / 8) / 256), dim3(256),
                           0, stream, Wq, scales, zeros, mask, scale2, Wb);
        hipLaunchKernelGGL(cvt_x_kernel, dim3((MDIM * NDIM / 8) / 256), dim3(256),
                           0, stream, x, Xb);
        hipFuncSetAttribute((const void*)gemm8p_kernel,
                            hipFuncAttributeMaxDynamicSharedMemorySize, 131072);
        hipLaunchKernelGGL(gemm8p_kernel, dim3((MDIM / 256) * (KDIM / 256)), dim3(512),
                           131072, stream, Xb, Wb, bias, out);
    } else {
        hipLaunchKernelGGL(naive_kernel, dim3((MDIM * KDIM) / 256), dim3(256),
                           0, stream, x, Wq, scales, zeros, mask, scale2, bias, out);
    }
}